// Round 2
// baseline (45.594 us; speedup 1.0000x reference)
//
#include <hip/hip_runtime.h>
#include <math.h>

#define SS 7
#define CH 30
#define NCLS 20
#define PRED_STRIDE (CH * SS * SS)   // 1470
#define IMGF 448.0f
#define BPB 8                         // batches per 256-thread block

__device__ __forceinline__ float sigf(float x) {
    return 1.0f / (1.0f + __expf(-x));
}

__global__ __launch_bounds__(256) void yolo_loss_kernel(
    const float* __restrict__ pred,
    const float* __restrict__ annot,
    float* __restrict__ out, int n)
{
    __shared__ float s_annot[BPB][10];
    __shared__ float s_cell[BPB][CH];
    __shared__ float s_nobj[BPB];
    __shared__ float s_red[BPB];

    const int tid  = threadIdx.x;
    const int bsub = tid >> 5;        // 0..7  : which batch in this block
    const int c    = tid & 31;        // 0..31 : channel lane
    const int b    = blockIdx.x * BPB + bsub;
    const bool valid = (b < n);

    if (tid < BPB) s_red[tid] = 0.0f;
    if (valid && c < 10)
        s_annot[bsub][c] = annot[(size_t)b * 10 + c];
    __syncthreads();

    // ---- grid-cell indices from box 1 (the gather cell), reference op order ----
    const float gx1 = s_annot[bsub][5], gy1 = s_annot[bsub][6];
    const float gw1 = s_annot[bsub][7], gh1 = s_annot[bsub][8];
    const int ti1 = (int)floorf((gx1 / IMGF + (gw1 / IMGF) * 0.5f) * 7.0f);
    const int tj1 = (int)floorf((gy1 / IMGF + (gh1 / IMGF) * 0.5f) * 7.0f);

    // ---- one gather per lane: channel c of batch b ----
    float sv = 0.0f;
    if (valid && c < CH) {
        float v = pred[(size_t)b * PRED_STRIDE + c * (SS * SS) + ti1 * SS + tj1];
        sv = sigf(v);
        s_cell[bsub][c] = sv;
    }

    // ---- lane 31: "last no-object cell" conf term ----
    if (valid && c == 31) {
        const float gx0 = s_annot[bsub][0], gy0 = s_annot[bsub][1];
        const float gw0 = s_annot[bsub][2], gh0 = s_annot[bsub][3];
        const int ti0 = (int)floorf((gx0 / IMGF + (gw0 / IMGF) * 0.5f) * 7.0f);
        const int tj0 = (int)floorf((gy0 / IMGF + (gh0 / IMGF) * 0.5f) * 7.0f);
        int last = 48;
        #pragma unroll 1
        for (int idx = 48; idx >= 0; --idx) {
            int i = idx / SS, j = idx % SS;
            bool m = ((i != ti0) && (j != tj0)) || ((i != ti1) && (j != tj1));
            if (m) { last = idx; break; }
        }
        float conf = sigf(pred[(size_t)b * PRED_STRIDE + 9 * (SS * SS) + last]);
        s_nobj[bsub] = 2.0f * conf * conf;   // nobj broadcast over the 2 annot boxes
    }

    // ---- class loss per-lane (uses own register value, no LDS dep) ----
    const int ci0 = (int)s_annot[bsub][4];
    const int ci1 = (int)s_annot[bsub][9];
    float clsq = 0.0f;
    if (valid && c >= 10 && c < CH) {
        float oh0 = ((c - 10) == ci0) ? 1.0f : 0.0f;
        float oh1 = ((c - 10) == ci1) ? 1.0f : 0.0f;
        float d0 = oh0 - sv, d1 = oh1 - sv;
        clsq = d0 * d0 + d1 * d1;
    }
    #pragma unroll
    for (int off = 16; off > 0; off >>= 1)
        clsq += __shfl_down(clsq, off, 32);   // group-of-32 reduce; lane c==0 holds sum

    __syncthreads();

    // ---- box/IoU/obj terms on one lane per batch ----
    if (valid && c == 0) {
        float b1x = s_cell[bsub][0], b1y = s_cell[bsub][1], b1w = s_cell[bsub][2],
              b1h = s_cell[bsub][3], b1c = s_cell[bsub][4];
        float b2x = s_cell[bsub][5], b2y = s_cell[bsub][6], b2w = s_cell[bsub][7],
              b2h = s_cell[bsub][8], b2c = s_cell[bsub][9];
        float total = clsq + s_nobj[bsub];
        #pragma unroll
        for (int k = 0; k < 2; ++k) {
            float gx = s_annot[bsub][k * 5 + 0], gy = s_annot[bsub][k * 5 + 1];
            float gw = s_annot[bsub][k * 5 + 2], gh = s_annot[bsub][k * 5 + 3];
            float x1, y1, x2, y2, inter, uni, iou1, iou2;

            x1 = fmaxf(b1x, gx); y1 = fmaxf(b1y, gy);
            x2 = fminf(b1x + b1w, gx + gw); y2 = fminf(b1y + b1h, gy + gh);
            inter = fmaxf(x2 - x1, 0.0f) * fmaxf(y2 - y1, 0.0f);
            uni = b1w * b1h + gw * gh - inter;
            iou1 = inter / (uni + 1e-6f);

            x1 = fmaxf(b2x, gx); y1 = fmaxf(b2y, gy);
            x2 = fminf(b2x + b2w, gx + gw); y2 = fminf(b2y + b2h, gy + gh);
            inter = fmaxf(x2 - x1, 0.0f) * fmaxf(y2 - y1, 0.0f);
            uni = b2w * b2h + gw * gh - inter;
            iou2 = inter / (uni + 1e-6f);

            bool p1 = iou1 > iou2;
            float sx = p1 ? b1x : b2x, sy = p1 ? b1y : b2y;
            float sw = p1 ? b1w : b2w, sh = p1 ? b1h : b2h;
            float sc = p1 ? b1c : b2c;

            float ngx = gx / IMGF, ngy = gy / IMGF, ngw = gw / IMGF, ngh = gh / IMGF;
            float dx = ngx - sx, dy = ngy - sy;
            float dw = sqrtf(ngw) - sqrtf(sw), dh = sqrtf(ngh) - sqrtf(sh);
            total += 5.0f * (dx * dx + dy * dy)
                   + 5.0f * (dw * dw + dh * dh)
                   + (1.0f - sc) * (1.0f - sc);
        }
        s_red[bsub] = total;
    }
    __syncthreads();

    // ---- block reduce: 8 partials -> one atomic per block ----
    if (tid == 0) {
        float t = 0.0f;
        #pragma unroll
        for (int q = 0; q < BPB; ++q) t += s_red[q];
        atomicAdd(out, t);
    }
}

extern "C" void kernel_launch(void* const* d_in, const int* in_sizes, int n_in,
                              void* d_out, int out_size, void* d_ws, size_t ws_size,
                              hipStream_t stream) {
    const float* pred  = (const float*)d_in[0];
    const float* annot = (const float*)d_in[1];
    float* out = (float*)d_out;
    int n = in_sizes[0] / PRED_STRIDE;   // 16384

    hipMemsetAsync(out, 0, sizeof(float) * out_size, stream);
    int blocks = (n + BPB - 1) / BPB;    // 2048
    yolo_loss_kernel<<<blocks, 256, 0, stream>>>(pred, annot, out, n);
}

// Round 3
// 30.786 us; speedup vs baseline: 1.4810x; 1.4810x over previous
//
#include <hip/hip_runtime.h>
#include <math.h>

#define SS 7
#define CH 30
#define NCLS 20
#define PRED_STRIDE (CH * SS * SS)   // 1470
#define IMGF 448.0f

__device__ __forceinline__ float sigf(float x) {
    return 1.0f / (1.0f + __expf(-x));
}

// One 32-lane group per batch element. Lane c: channel gather (c<30),
// class-loss term (10<=c<30), no-object term (c==31), box/IoU terms (c==0).
// Per-wave shuffle reduce -> plain store to partial[waveId]. No atomics, no LDS.
__global__ __launch_bounds__(256) void yolo_main(
    const float* __restrict__ pred,
    const float* __restrict__ annot,
    float* __restrict__ partial, int n)
{
    const int gt   = blockIdx.x * blockDim.x + threadIdx.x;
    const int b    = gt >> 5;         // batch = global 32-lane group
    const int c    = gt & 31;         // channel lane
    float contrib = 0.0f;

    if (b < n) {
        const float* g = annot + (size_t)b * 10;

        // all lanes need box-1 geometry for the gather cell (reference op order)
        const float a5 = g[5], a6 = g[6], a7 = g[7], a8 = g[8];
        const int ti1 = (int)floorf((a5 / IMGF + (a7 / IMGF) * 0.5f) * 7.0f);
        const int tj1 = (int)floorf((a6 / IMGF + (a8 / IMGF) * 0.5f) * 7.0f);

        // one gather per lane
        float sv = 0.0f;
        if (c < CH)
            sv = sigf(pred[(size_t)b * PRED_STRIDE + c * (SS * SS) + ti1 * SS + tj1]);

        // class loss on lanes 10..29 (own register value)
        if (c >= 10 && c < CH) {
            const int ci0 = (int)g[4];
            const int ci1 = (int)g[9];
            float oh0 = ((c - 10) == ci0) ? 1.0f : 0.0f;
            float oh1 = ((c - 10) == ci1) ? 1.0f : 0.0f;
            float d0 = oh0 - sv, d1 = oh1 - sv;
            contrib = d0 * d0 + d1 * d1;
        }

        // no-object term on lane 31
        if (c == 31) {
            const float a0 = g[0], a1 = g[1], a2 = g[2], a3 = g[3];
            const int ti0 = (int)floorf((a0 / IMGF + (a2 / IMGF) * 0.5f) * 7.0f);
            const int tj0 = (int)floorf((a1 / IMGF + (a3 / IMGF) * 0.5f) * 7.0f);
            int last = 48;
            #pragma unroll 1
            for (int idx = 48; idx >= 0; --idx) {
                int i = idx / SS, j = idx % SS;
                bool m = ((i != ti0) && (j != tj0)) || ((i != ti1) && (j != tj1));
                if (m) { last = idx; break; }
            }
            float conf = sigf(pred[(size_t)b * PRED_STRIDE + 9 * (SS * SS) + last]);
            contrib += 2.0f * conf * conf;   // nobj broadcast over 2 annot boxes
        }

        // share cell[0..9] within the 32-lane group (width-32 shuffle)
        float cell[10];
        #pragma unroll
        for (int j = 0; j < 10; ++j) cell[j] = __shfl(sv, j, 32);

        // box / IoU / obj terms on lane 0 of the group
        if (c == 0) {
            float b1x = cell[0], b1y = cell[1], b1w = cell[2], b1h = cell[3], b1c = cell[4];
            float b2x = cell[5], b2y = cell[6], b2w = cell[7], b2h = cell[8], b2c = cell[9];
            #pragma unroll
            for (int k = 0; k < 2; ++k) {
                float gx = g[k * 5 + 0], gy = g[k * 5 + 1];
                float gw = g[k * 5 + 2], gh = g[k * 5 + 3];
                float x1, y1, x2, y2, inter, uni, iou1, iou2;

                x1 = fmaxf(b1x, gx); y1 = fmaxf(b1y, gy);
                x2 = fminf(b1x + b1w, gx + gw); y2 = fminf(b1y + b1h, gy + gh);
                inter = fmaxf(x2 - x1, 0.0f) * fmaxf(y2 - y1, 0.0f);
                uni = b1w * b1h + gw * gh - inter;
                iou1 = inter / (uni + 1e-6f);

                x1 = fmaxf(b2x, gx); y1 = fmaxf(b2y, gy);
                x2 = fminf(b2x + b2w, gx + gw); y2 = fminf(b2y + b2h, gy + gh);
                inter = fmaxf(x2 - x1, 0.0f) * fmaxf(y2 - y1, 0.0f);
                uni = b2w * b2h + gw * gh - inter;
                iou2 = inter / (uni + 1e-6f);

                bool p1 = iou1 > iou2;
                float sx = p1 ? b1x : b2x, sy = p1 ? b1y : b2y;
                float sw = p1 ? b1w : b2w, sh = p1 ? b1h : b2h;
                float sc = p1 ? b1c : b2c;

                float ngx = gx / IMGF, ngy = gy / IMGF, ngw = gw / IMGF, ngh = gh / IMGF;
                float dx = ngx - sx, dy = ngy - sy;
                float dw = sqrtf(ngw) - sqrtf(sw), dh = sqrtf(ngh) - sqrtf(sh);
                contrib += 5.0f * (dx * dx + dy * dy)
                         + 5.0f * (dw * dw + dh * dh)
                         + (1.0f - sc) * (1.0f - sc);
            }
        }
    }

    // wave64 reduce (covers both 32-groups in the wave) -> one plain store/wave
    #pragma unroll
    for (int off = 32; off > 0; off >>= 1)
        contrib += __shfl_down(contrib, off, 64);
    if ((threadIdx.x & 63) == 0)
        partial[gt >> 6] = contrib;
}

// Single-block final reduce: 8192 partials -> out[0] (plain store, no memset).
__global__ __launch_bounds__(256) void yolo_reduce(
    const float* __restrict__ partial, float* __restrict__ out, int m)
{
    float s = 0.0f;
    for (int i = threadIdx.x; i < m; i += 256) s += partial[i];
    #pragma unroll
    for (int off = 32; off > 0; off >>= 1)
        s += __shfl_down(s, off, 64);
    __shared__ float sm[4];
    if ((threadIdx.x & 63) == 0) sm[threadIdx.x >> 6] = s;
    __syncthreads();
    if (threadIdx.x == 0) out[0] = sm[0] + sm[1] + sm[2] + sm[3];
}

extern "C" void kernel_launch(void* const* d_in, const int* in_sizes, int n_in,
                              void* d_out, int out_size, void* d_ws, size_t ws_size,
                              hipStream_t stream) {
    const float* pred  = (const float*)d_in[0];
    const float* annot = (const float*)d_in[1];
    float* out = (float*)d_out;
    float* partial = (float*)d_ws;
    int n = in_sizes[0] / PRED_STRIDE;   // 16384

    int threads = 256;
    int groups_needed = n;                         // one 32-lane group per batch
    int blocks = (groups_needed * 32 + threads - 1) / threads;   // 2048
    int nwaves = blocks * (threads / 64);          // 8192 partials

    yolo_main<<<blocks, threads, 0, stream>>>(pred, annot, partial, n);
    yolo_reduce<<<1, threads, 0, stream>>>(partial, out, nwaves);
}

// Round 4
// 24.359 us; speedup vs baseline: 1.8717x; 1.2638x over previous
//
#include <hip/hip_runtime.h>
#include <math.h>

#define SS 7
#define CH 30
#define NCLS 20
#define PRED_STRIDE (CH * SS * SS)   // 1470
#define IMGF 448.0f

__device__ __forceinline__ float sigf(float x) {
    return 1.0f / (1.0f + __expf(-x));
}

// 4-lane quad per batch: lane r gathers channels {r, r+4, ..., <30} (8-deep ILP).
// cell[0..9] exchanged via static __shfl within the quad. Box/IoU on r==0,
// nobj on r==3, class loss on owning lanes. Block reduce -> 1 atomic per block.
__global__ __launch_bounds__(256) void yolo_main(
    const float* __restrict__ pred,
    const float* __restrict__ annot,
    float* __restrict__ out, int n)
{
    const int tid  = threadIdx.x;
    const int lane = tid & 63;
    const int r    = tid & 3;                       // lane within quad
    const int b    = blockIdx.x * 64 + (tid >> 2);  // batch for this quad
    float contrib = 0.0f;

    if (b < n) {
        const float* g = annot + (size_t)b * 10;

        // gather cell indices from annot box 1 (reference op order)
        const float a5 = g[5], a6 = g[6], a7 = g[7], a8 = g[8];
        const int ti1 = (int)floorf((a5 / IMGF + (a7 / IMGF) * 0.5f) * 7.0f);
        const int tj1 = (int)floorf((a6 / IMGF + (a8 / IMGF) * 0.5f) * 7.0f);

        // 8 independent gathers per lane: channels c = r + 4*j
        const float* base = pred + (size_t)b * PRED_STRIDE + ti1 * SS + tj1;
        float sv[8];
        #pragma unroll
        for (int j = 0; j < 8; ++j) {
            int c = r + 4 * j;
            sv[j] = (c < CH) ? base[c * (SS * SS)] : 0.0f;
        }
        #pragma unroll
        for (int j = 0; j < 8; ++j) sv[j] = sigf(sv[j]);

        // class loss on owning lanes (channels 10..29)
        const int ci0 = (int)g[4];
        const int ci1 = (int)g[9];
        #pragma unroll
        for (int j = 0; j < 8; ++j) {
            int c = r + 4 * j;
            if (c >= 10 && c < CH) {
                int cc = c - 10;
                float oh0 = (cc == ci0) ? 1.0f : 0.0f;
                float oh1 = (cc == ci1) ? 1.0f : 0.0f;
                float d0 = oh0 - sv[j], d1 = oh1 - sv[j];
                contrib += d0 * d0 + d1 * d1;
            }
        }

        // no-object term on quad lane 3 (has only 7 gathers)
        if (r == 3) {
            const float a0 = g[0], a1 = g[1], a2 = g[2], a3 = g[3];
            const int ti0 = (int)floorf((a0 / IMGF + (a2 / IMGF) * 0.5f) * 7.0f);
            const int tj0 = (int)floorf((a1 / IMGF + (a3 / IMGF) * 0.5f) * 7.0f);
            int last = 48;
            #pragma unroll 1
            for (int idx = 48; idx >= 0; --idx) {
                int i = idx / SS, j = idx % SS;
                bool m = ((i != ti0) && (j != tj0)) || ((i != ti1) && (j != tj1));
                if (m) { last = idx; break; }
            }
            float conf = sigf(pred[(size_t)b * PRED_STRIDE + 9 * (SS * SS) + last]);
            contrib += 2.0f * conf * conf;   // nobj broadcast over 2 annot boxes
        }

        // exchange cell[0..9] within the quad: channel c lives in reg (c>>2)
        // of lane (quadbase + (c&3)) — all indices static after unroll
        const int qb = lane & ~3;
        float cell[10];
        #pragma unroll
        for (int c = 0; c < 10; ++c)
            cell[c] = __shfl(sv[c >> 2], qb + (c & 3), 64);

        // box / IoU / obj terms on quad lane 0
        if (r == 0) {
            float b1x = cell[0], b1y = cell[1], b1w = cell[2], b1h = cell[3], b1c = cell[4];
            float b2x = cell[5], b2y = cell[6], b2w = cell[7], b2h = cell[8], b2c = cell[9];
            #pragma unroll
            for (int k = 0; k < 2; ++k) {
                float gx = g[k * 5 + 0], gy = g[k * 5 + 1];
                float gw = g[k * 5 + 2], gh = g[k * 5 + 3];
                float x1, y1, x2, y2, inter, uni, iou1, iou2;

                x1 = fmaxf(b1x, gx); y1 = fmaxf(b1y, gy);
                x2 = fminf(b1x + b1w, gx + gw); y2 = fminf(b1y + b1h, gy + gh);
                inter = fmaxf(x2 - x1, 0.0f) * fmaxf(y2 - y1, 0.0f);
                uni = b1w * b1h + gw * gh - inter;
                iou1 = inter / (uni + 1e-6f);

                x1 = fmaxf(b2x, gx); y1 = fmaxf(b2y, gy);
                x2 = fminf(b2x + b2w, gx + gw); y2 = fminf(b2y + b2h, gy + gh);
                inter = fmaxf(x2 - x1, 0.0f) * fmaxf(y2 - y1, 0.0f);
                uni = b2w * b2h + gw * gh - inter;
                iou2 = inter / (uni + 1e-6f);

                bool p1 = iou1 > iou2;
                float sx = p1 ? b1x : b2x, sy = p1 ? b1y : b2y;
                float sw = p1 ? b1w : b2w, sh = p1 ? b1h : b2h;
                float sc = p1 ? b1c : b2c;

                float ngx = gx / IMGF, ngy = gy / IMGF, ngw = gw / IMGF, ngh = gh / IMGF;
                float dx = ngx - sx, dy = ngy - sy;
                float dw = sqrtf(ngw) - sqrtf(sw), dh = sqrtf(ngh) - sqrtf(sh);
                contrib += 5.0f * (dx * dx + dy * dy)
                         + 5.0f * (dw * dw + dh * dh)
                         + (1.0f - sc) * (1.0f - sc);
            }
        }
    }

    // wave64 reduce -> 4 partials in LDS -> one atomic per block
    #pragma unroll
    for (int off = 32; off > 0; off >>= 1)
        contrib += __shfl_down(contrib, off, 64);

    __shared__ float sm[4];
    if ((tid & 63) == 0) sm[tid >> 6] = contrib;
    __syncthreads();
    if (tid == 0)
        atomicAdd(out, sm[0] + sm[1] + sm[2] + sm[3]);
}

extern "C" void kernel_launch(void* const* d_in, const int* in_sizes, int n_in,
                              void* d_out, int out_size, void* d_ws, size_t ws_size,
                              hipStream_t stream) {
    const float* pred  = (const float*)d_in[0];
    const float* annot = (const float*)d_in[1];
    float* out = (float*)d_out;
    int n = in_sizes[0] / PRED_STRIDE;   // 16384

    hipMemsetAsync(out, 0, sizeof(float) * out_size, stream);
    int blocks = (n + 63) / 64;          // 256 blocks x 256 threads, quad per batch
    yolo_main<<<blocks, 256, 0, stream>>>(pred, annot, out, n);
}